// Round 4
// baseline (10660.689 us; speedup 1.0000x reference)
//
#include <hip/hip_runtime.h>

// GRU: B=256, T=512, F=256, H=512, C=10  (MI355X / gfx950)
// XCD-local persistent kernel with TWO-set software pipelining:
//  - 8 groups (1/XCD) x 32 batch rows; group = 8 WGs x 64 cols (4 waves x 16).
//  - Each WG processes row-set A (rows g*32..+15) and B (+16..+31) with the
//    SAME weight registers; phases ping-pong A/B so barrier convergence of one
//    set hides under the other set's compute.
//  - h / r*h exchange stays in the XCD's L2: plain stores + vmcnt(0), sc0
//    loads, L2-resident atomic counters. No wbl2/inv in the hot loop.

#define BB 256
#define TT 512
#define FF 256
#define HH 512
#define GROUP_WGS 8

typedef short short8 __attribute__((ext_vector_type(8)));
typedef short short4v __attribute__((ext_vector_type(4)));
typedef float float4v __attribute__((ext_vector_type(4)));
typedef unsigned long long u64;

// ws layout (bytes)
#define WFRAG_OFF 0
#define WFRAG_BYTES (32 * 3 * 24 * 64 * 8 * 2)            // 2,359,296
#define HBUF_OFF (WFRAG_OFF + WFRAG_BYTES)                 // bf16 h   [256][512]
#define RHBUF_OFF (HBUF_OFF + BB * HH * 2)                 // bf16 r*h [256][512]
#define HFIN_OFF (RHBUF_OFF + BB * HH * 2)                 // f32 h_final [256][512]
#define CTRL_OFF (HFIN_OFF + BB * HH * 4)                  // claims + barriers
#define CTRL_BYTES 4096
#define XB_OFF (CTRL_OFF + CTRL_BYTES)                     // bf16 x [256][512][256]
#define XB_BYTES ((size_t)BB * TT * FF * 2)
#define WS_XB_NEEDED ((size_t)XB_OFF + XB_BYTES)

__device__ __forceinline__ short f2bf(float f) {
  unsigned u = __builtin_bit_cast(unsigned, f);
  u += 0x7fffu + ((u >> 16) & 1u);            // RNE to bf16
  return (short)(u >> 16);
}
__device__ __forceinline__ float sigm(float v) { return 1.0f / (1.0f + __expf(-v)); }
__device__ __forceinline__ float tanh_(float v) { return 2.0f / (1.0f + __expf(-2.0f * v)) - 1.0f; }

__device__ __forceinline__ float4v mfma_bf16(short8 a, short8 b, float4v c) {
  return __builtin_amdgcn_mfma_f32_16x16x32_bf16(a, b, c, 0, 0, 0);
}

// ---- weight prep: f32 [768][512] -> bf16 MFMA B-fragments ----
__global__ void prep_w(const float* __restrict__ Wz, const float* __restrict__ Wr,
                       const float* __restrict__ Wh, short* __restrict__ wfrag) {
  int id = blockIdx.x * 256 + threadIdx.x;     // 576*256 == 32*3*24*64
  int lane = id & 63;
  int rest = id >> 6;
  int kk = rest % 24;
  int gc = rest / 24;
  int g = gc % 3;
  int cb = gc / 3;
  if (cb >= 32) return;
  const float* W = (g == 0) ? Wz : ((g == 1) ? Wr : Wh);
  int n = cb * 16 + (lane & 15);
  int kbase = kk * 32 + (lane >> 4) * 8;
  short8 v;
#pragma unroll
  for (int j = 0; j < 8; ++j) v[j] = f2bf(W[(size_t)(kbase + j) * HH + n]);
  *(((short8*)wfrag) + id) = v;
}

// ---- x prep: f32 -> bf16 ----
__global__ void xprep(const float* __restrict__ x, short* __restrict__ xb) {
  size_t i = (size_t)blockIdx.x * 256 + threadIdx.x;
  const float4v* src = (const float4v*)x;
  float4v a = src[i * 2], b = src[i * 2 + 1];
  short8 v;
  v[0] = f2bf(a[0]); v[1] = f2bf(a[1]); v[2] = f2bf(a[2]); v[3] = f2bf(a[3]);
  v[4] = f2bf(b[0]); v[5] = f2bf(b[1]); v[6] = f2bf(b[2]); v[7] = f2bf(b[3]);
  *(((short8*)xb) + i) = v;
}

// ---- XCD-local barrier primitives ----
__device__ __forceinline__ void bar_arrive(int* bar) {
  asm volatile("s_waitcnt vmcnt(0)" ::: "memory");  // stores acked in XCD L2
  __syncthreads();
  if (threadIdx.x == 0)
    __hip_atomic_fetch_add(bar, 1, __ATOMIC_RELAXED, __HIP_MEMORY_SCOPE_WORKGROUP);
}
__device__ __forceinline__ void bar_wait(int* bar, int tgt) {
  if (threadIdx.x == 0) {
    while (__hip_atomic_load(bar, __ATOMIC_RELAXED, __HIP_MEMORY_SCOPE_AGENT) < tgt) {}
  }
  __syncthreads();
}

// sc0 (L1-bypass) 16B fragment load from XCD L2
__device__ __forceinline__ short8 ld_frag(const short* p) {
  const u64* q = (const u64*)p;
  u64 lo = __hip_atomic_load(q, __ATOMIC_RELAXED, __HIP_MEMORY_SCOPE_AGENT);
  u64 hi = __hip_atomic_load(q + 1, __ATOMIC_RELAXED, __HIP_MEMORY_SCOPE_AGENT);
  short4v l4 = __builtin_bit_cast(short4v, lo);
  short4v h4 = __builtin_bit_cast(short4v, hi);
  return __builtin_shufflevector(l4, h4, 0, 1, 2, 3, 4, 5, 6, 7);
}

// ---- per-set phase helpers (inlined; arrays stay statically indexed) ----
__device__ __forceinline__ void gate_phase1(const short* hb_lane,
    const short8 (&wz)[24], const short8 (&wr)[24],
    float4v azx, float4v arx, float bz, float br,
    float4v& z, float4v& rr) {
  float4v az = azx, ar = arx;
#pragma unroll
  for (int kk = 0; kk < 16; ++kk) {
    short8 a = ld_frag(hb_lane + kk * 32);
    az = mfma_bf16(a, wz[kk], az);
    ar = mfma_bf16(a, wr[kk], ar);
  }
#pragma unroll
  for (int i = 0; i < 4; ++i) {
    z[i] = sigm(az[i] + bz);
    rr[i] = sigm(ar[i] + br);
  }
}

__device__ __forceinline__ float4v gate_phase2(const short* rh_lane,
    const short8 (&wh)[24], float4v ahx, float bh, float4v z, float4v h_loc) {
  float4v ah = ahx;
#pragma unroll
  for (int kk = 0; kk < 16; ++kk) {
    short8 a = ld_frag(rh_lane + kk * 32);
    ah = mfma_bf16(a, wh[kk], ah);
  }
  float4v hn;
#pragma unroll
  for (int i = 0; i < 4; ++i) {
    float hv = tanh_(ah[i] + bh);
    hn[i] = (1.0f - z[i]) * h_loc[i] + z[i] * hv;
  }
  return hn;
}

template <bool XB>
__device__ __forceinline__ void load_xf(short8 (&xf)[8], const short* xb_l,
                                        const float* xf_l, int t) {
#pragma unroll
  for (int kx = 0; kx < 8; ++kx) {
    if constexpr (XB) {
      xf[kx] = *(const short8*)(xb_l + (size_t)t * FF + kx * 32);
    } else {
      const float* xl = xf_l + (size_t)t * FF;
      float4v a = *(const float4v*)(xl + kx * 32);
      float4v b2 = *(const float4v*)(xl + kx * 32 + 4);
      short8 v;
      v[0] = f2bf(a[0]); v[1] = f2bf(a[1]); v[2] = f2bf(a[2]); v[3] = f2bf(a[3]);
      v[4] = f2bf(b2[0]); v[5] = f2bf(b2[1]); v[6] = f2bf(b2[2]); v[7] = f2bf(b2[3]);
      xf[kx] = v;
    }
  }
}

__device__ __forceinline__ void prime_x(const short8 (&xf)[8],
    const short8 (&wz)[24], const short8 (&wr)[24], const short8 (&wh)[24],
    float4v& azx, float4v& arx, float4v& ahx) {
  azx = (float4v){0.f, 0.f, 0.f, 0.f};
  arx = (float4v){0.f, 0.f, 0.f, 0.f};
  ahx = (float4v){0.f, 0.f, 0.f, 0.f};
#pragma unroll
  for (int kx = 0; kx < 8; ++kx) {
    azx = mfma_bf16(xf[kx], wz[16 + kx], azx);
    arx = mfma_bf16(xf[kx], wr[16 + kx], arx);
    ahx = mfma_bf16(xf[kx], wh[16 + kx], ahx);
  }
}

template <bool XB>
__global__ __launch_bounds__(256, 1) void gru_kernel(
    const void* __restrict__ xv, const short* __restrict__ wfrag,
    short* __restrict__ hbuf, short* __restrict__ rhbuf,
    float* __restrict__ hfin, int* __restrict__ ctrl,
    const float* __restrict__ bzv, const float* __restrict__ brv,
    const float* __restrict__ bhv) {
  // ---- claim a slot in this XCD (8 workers per XCD) ----
  __shared__ int s_slot, s_xcc;
  if (threadIdx.x == 0) {
    unsigned xcc;
    asm volatile("s_getreg_b32 %0, hwreg(HW_REG_XCC_ID)" : "=s"(xcc));
    xcc &= 7u;
    s_xcc = (int)xcc;
    s_slot = atomicAdd(ctrl + xcc * 16, 1);   // device-scope claim
  }
  __syncthreads();
  const int slot = s_slot;
  if (slot >= GROUP_WGS) return;               // surplus WG
  const int group = s_xcc;                     // 0..7, one group per XCD
  const int member = slot;                     // 0..7 -> 64-col block

  const int tid = threadIdx.x;
  const int w = tid >> 6;
  const int l = tid & 63;
  const int l15 = l & 15;
  const int lhi = l >> 4;
  const int cbg = member * 4 + w;              // 16-col block 0..31
  const int jc = cbg * 16;
  const int rbA = group * 32;                  // set A rows
  const int rbB = rbA + 16;                    // set B rows

  // ---- weights -> registers ----
  const short8* wf = (const short8*)wfrag;
  short8 wz[24], wr[24], wh[24];
#pragma unroll
  for (int kk = 0; kk < 24; ++kk) wz[kk] = wf[((cbg * 3 + 0) * 24 + kk) * 64 + l];
#pragma unroll
  for (int kk = 0; kk < 24; ++kk) wr[kk] = wf[((cbg * 3 + 1) * 24 + kk) * 64 + l];
#pragma unroll
  for (int kk = 0; kk < 24; ++kk) wh[kk] = wf[((cbg * 3 + 2) * 24 + kk) * 64 + l];

  const float bz = bzv[jc + l15], br = brv[jc + l15], bh = bhv[jc + l15];

  const int drowA = rbA + lhi * 4, drowB = rbB + lhi * 4;
  const int dcol = jc + l15;

  const short* hbA = hbuf + (size_t)(rbA + l15) * HH + lhi * 8;
  const short* hbB = hbuf + (size_t)(rbB + l15) * HH + lhi * 8;
  const short* rhA = rhbuf + (size_t)(rbA + l15) * HH + lhi * 8;
  const short* rhB = rhbuf + (size_t)(rbB + l15) * HH + lhi * 8;
  const float* xfA32 = XB ? nullptr : ((const float*)xv + (size_t)(rbA + l15) * TT * FF + lhi * 8);
  const float* xfB32 = XB ? nullptr : ((const float*)xv + (size_t)(rbB + l15) * TT * FF + lhi * 8);
  const short* xbA = XB ? ((const short*)xv + (size_t)(rbA + l15) * TT * FF + lhi * 8) : nullptr;
  const short* xbB = XB ? ((const short*)xv + (size_t)(rbB + l15) * TT * FF + lhi * 8) : nullptr;

  float4v h_locA = {0.f, 0.f, 0.f, 0.f}, h_locB = {0.f, 0.f, 0.f, 0.f};
  int tgtA = 0, tgtB = 0;
  int* barA = ctrl + 128 + group * 32;         // 64B apart per counter
  int* barB = barA + 16;

  // ---- prime t=0 ----
  float4v azxA, arxA, ahxA, azxB, arxB, ahxB;
  {
    short8 xf[8];
    load_xf<XB>(xf, xbA, xfA32, 0);
    prime_x(xf, wz, wr, wh, azxA, arxA, ahxA);
    load_xf<XB>(xf, xbB, xfB32, 0);
    prime_x(xf, wz, wr, wh, azxB, arxB, ahxB);
  }

#pragma unroll 1
  for (int t = 0; t < TT; ++t) {
    // ===== P1A: z,r for set A =====
    if (t) bar_wait(barA, tgtA);               // prev P2A h-stores visible
    float4v zA, rrA;
    gate_phase1(hbA, wz, wr, azxA, arxA, bz, br, zA, rrA);
#pragma unroll
    for (int i = 0; i < 4; ++i)
      rhbuf[(size_t)(drowA + i) * HH + dcol] = f2bf(rrA[i] * h_locA[i]);
    tgtA += GROUP_WGS;
    bar_arrive(barA);

    // ===== P1B =====
    if (t) bar_wait(barB, tgtB);
    float4v zB, rrB;
    gate_phase1(hbB, wz, wr, azxB, arxB, bz, br, zB, rrB);
#pragma unroll
    for (int i = 0; i < 4; ++i)
      rhbuf[(size_t)(drowB + i) * HH + dcol] = f2bf(rrB[i] * h_locB[i]);
    tgtB += GROUP_WGS;
    bar_arrive(barB);

    // ===== P2A: h_tilde + update =====
    bar_wait(barA, tgtA);                      // rhA visible
    h_locA = gate_phase2(rhA, wh, ahxA, bh, zA, h_locA);
    if (t + 1 < TT) {
#pragma unroll
      for (int i = 0; i < 4; ++i)
        hbuf[(size_t)(drowA + i) * HH + dcol] = f2bf(h_locA[i]);
      tgtA += GROUP_WGS;
      bar_arrive(barA);
    } else {
#pragma unroll
      for (int i = 0; i < 4; ++i)
        hfin[(size_t)(drowA + i) * HH + dcol] = h_locA[i];
    }

    // ===== P2B =====
    bar_wait(barB, tgtB);
    h_locB = gate_phase2(rhB, wh, ahxB, bh, zB, h_locB);
    if (t + 1 < TT) {
#pragma unroll
      for (int i = 0; i < 4; ++i)
        hbuf[(size_t)(drowB + i) * HH + dcol] = f2bf(h_locB[i]);
      tgtB += GROUP_WGS;
      bar_arrive(barB);
    } else {
#pragma unroll
      for (int i = 0; i < 4; ++i)
        hfin[(size_t)(drowB + i) * HH + dcol] = h_locB[i];
    }

    // ===== prefetch x(t+1) + prime gate x-contributions (overlaps next waits) =====
    if (t + 1 < TT) {
      short8 xf[8];
      load_xf<XB>(xf, xbA, xfA32, t + 1);
      prime_x(xf, wz, wr, wh, azxA, arxA, ahxA);
      load_xf<XB>(xf, xbB, xfB32, t + 1);
      prime_x(xf, wz, wr, wh, azxB, arxB, ahxB);
    }
  }
}

// out[b, c] = h_final[b,:] @ fc_w[:,c] + fc_b[c]
__global__ void fc_kernel(const float* __restrict__ hfin, const float* __restrict__ fw,
                          const float* __restrict__ fb, float* __restrict__ out) {
  int b = blockIdx.x;
  int tid = threadIdx.x;  // 64
  float p[10];
#pragma unroll
  for (int c = 0; c < 10; ++c) p[c] = 0.f;
  for (int k = tid; k < HH; k += 64) {
    float hv = hfin[(size_t)b * HH + k];
#pragma unroll
    for (int c = 0; c < 10; ++c) p[c] += hv * fw[k * 10 + c];
  }
#pragma unroll
  for (int c = 0; c < 10; ++c) {
    float v = p[c];
    for (int off = 32; off > 0; off >>= 1) v += __shfl_down(v, off);
    if (tid == 0) out[b * 10 + c] = v + fb[c];
  }
}

extern "C" void kernel_launch(void* const* d_in, const int* in_sizes, int n_in,
                              void* d_out, int out_size, void* d_ws, size_t ws_size,
                              hipStream_t stream) {
  const float* x = (const float*)d_in[0];
  const float* Wz_w = (const float*)d_in[1];
  const float* Wz_b = (const float*)d_in[2];
  const float* Wr_w = (const float*)d_in[3];
  const float* Wr_b = (const float*)d_in[4];
  const float* Wh_w = (const float*)d_in[5];
  const float* Wh_b = (const float*)d_in[6];
  const float* fc_w = (const float*)d_in[7];
  const float* fc_b = (const float*)d_in[8];

  char* ws = (char*)d_ws;
  short* wfrag = (short*)(ws + WFRAG_OFF);
  short* hbuf = (short*)(ws + HBUF_OFF);
  short* rhbuf = (short*)(ws + RHBUF_OFF);
  float* hfin = (float*)(ws + HFIN_OFF);
  int* ctrl = (int*)(ws + CTRL_OFF);
  short* xb = (short*)(ws + XB_OFF);

  // h0 = 0, claim + barrier counters = 0 (EVERY launch)
  hipMemsetAsync(hbuf, 0, BB * HH * 2, stream);
  hipMemsetAsync(ctrl, 0, CTRL_BYTES, stream);

  prep_w<<<576, 256, 0, stream>>>(Wz_w, Wr_w, Wh_w, wfrag);

  if (ws_size >= WS_XB_NEEDED) {
    xprep<<<(BB * TT * FF / 8) / 256, 256, 0, stream>>>(x, xb);
    gru_kernel<true><<<256, 256, 0, stream>>>(xb, wfrag, hbuf, rhbuf, hfin, ctrl,
                                              Wz_b, Wr_b, Wh_b);
  } else {
    gru_kernel<false><<<256, 256, 0, stream>>>(x, wfrag, hbuf, rhbuf, hfin, ctrl,
                                               Wz_b, Wr_b, Wh_b);
  }
  fc_kernel<<<BB, 64, 0, stream>>>(hfin, fc_w, fc_b, (float*)d_out);
}

// Round 5
// 9264.784 us; speedup vs baseline: 1.1507x; 1.1507x over previous
//
#include <hip/hip_runtime.h>

// GRU: B=256, T=512, F=256, H=512, C=10  (MI355X / gfx950)
// Round 5: x-projections precomputed by a parallel GEMM (xz/xr/xh for all B,T,
// biases folded, bf16). Recurrent loop touches only XCD-L2-local h / r*h plus
// a tiny prefetched xproj read. Per-wave flag barriers (no atomics RMW, no
// __syncthreads in the hot loop). 8 XCD-local groups x 32 rows (2 sets A/B
// ping-ponged) x 8 WGs x 4 waves x 16 cols; h-part weights (192 VGPR) in regs.

#define BB 256
#define TT 512
#define FF 256
#define HH 512
#define HX 1536
#define GROUP_WGS 8

typedef short short8 __attribute__((ext_vector_type(8)));
typedef short short4v __attribute__((ext_vector_type(4)));
typedef float float4v __attribute__((ext_vector_type(4)));
typedef unsigned long long u64;

// ws layout (bytes)
#define WFRAG_OFF 0
#define WFRAG_BYTES (32 * 3 * 24 * 64 * 8 * 2)            // 2,359,296
#define HBUF_OFF (WFRAG_OFF + WFRAG_BYTES)                 // bf16 h   [256][512]
#define RHBUF_OFF (HBUF_OFF + BB * HH * 2)                 // bf16 r*h [256][512]
#define HFIN_OFF (RHBUF_OFF + BB * HH * 2)                 // f32 h_final
#define CTRL_OFF (HFIN_OFF + BB * HH * 4)                  // claims + flags
#define CTRL_BYTES 16384
#define XBASE_OFF (CTRL_OFF + CTRL_BYTES)
#define XB_BYTES ((size_t)BB * TT * FF * 2)                // 67 MB (mode 1)
#define XPROJ_BYTES ((size_t)BB * TT * HX * 2)             // 402 MB (mode 2)
#define WS_M2 ((size_t)XBASE_OFF + XPROJ_BYTES)
#define WS_M1 ((size_t)XBASE_OFF + XB_BYTES)

__device__ __forceinline__ short f2bf(float f) {
  unsigned u = __builtin_bit_cast(unsigned, f);
  u += 0x7fffu + ((u >> 16) & 1u);            // RNE to bf16
  return (short)(u >> 16);
}
__device__ __forceinline__ float bf2f(unsigned short u) {
  return __builtin_bit_cast(float, (unsigned)u << 16);
}
__device__ __forceinline__ float sigm(float v) { return 1.0f / (1.0f + __expf(-v)); }
__device__ __forceinline__ float tanh_(float v) { return 2.0f / (1.0f + __expf(-2.0f * v)) - 1.0f; }
__device__ __forceinline__ float4v mfma_bf16(short8 a, short8 b, float4v c) {
  return __builtin_amdgcn_mfma_f32_16x16x32_bf16(a, b, c, 0, 0, 0);
}

// ---- weight prep: f32 [768][512] -> bf16 MFMA B-fragments ----
// Frag (cb, g, kk, lane, j): n = cb*16 + (lane&15), k = kk*32 + (lane>>4)*8 + j.
__global__ void prep_w(const float* __restrict__ Wz, const float* __restrict__ Wr,
                       const float* __restrict__ Wh, short* __restrict__ wfrag) {
  int id = blockIdx.x * 256 + threadIdx.x;     // 576*256 == 32*3*24*64
  int lane = id & 63;
  int rest = id >> 6;
  int kk = rest % 24;
  int gc = rest / 24;
  int g = gc % 3;
  int cb = gc / 3;
  if (cb >= 32) return;
  const float* W = (g == 0) ? Wz : ((g == 1) ? Wr : Wh);
  int n = cb * 16 + (lane & 15);
  int kbase = kk * 32 + (lane >> 4) * 8;
  short8 v;
#pragma unroll
  for (int j = 0; j < 8; ++j) v[j] = f2bf(W[(size_t)(kbase + j) * HH + n]);
  *(((short8*)wfrag) + id) = v;
}

// ---- x prep (mode 1 fallback): f32 -> bf16 ----
__global__ void xprep(const float* __restrict__ x, short* __restrict__ xb) {
  size_t i = (size_t)blockIdx.x * 256 + threadIdx.x;
  const float4v* src = (const float4v*)x;
  float4v a = src[i * 2], b = src[i * 2 + 1];
  short8 v;
  v[0] = f2bf(a[0]); v[1] = f2bf(a[1]); v[2] = f2bf(a[2]); v[3] = f2bf(a[3]);
  v[4] = f2bf(b[0]); v[5] = f2bf(b[1]); v[6] = f2bf(b[2]); v[7] = f2bf(b[3]);
  *(((short8*)xb) + i) = v;
}

// ---- xproj GEMM (mode 2): [BT,256] @ x-part weights -> bf16 [BT][3*512], bias folded ----
__global__ __launch_bounds__(256) void xproj_gemm(
    const float* __restrict__ x, const short* __restrict__ wfrag,
    const float* __restrict__ bz, const float* __restrict__ br,
    const float* __restrict__ bh, short* __restrict__ xp) {
  const int w = threadIdx.x >> 6, l = threadIdx.x & 63;
  const int l15 = l & 15, lhi = l >> 4;
  const size_t row0 = (size_t)blockIdx.x * 64 + w * 16;
  const float* xl = x + (row0 + l15) * FF + lhi * 8;
  short8 xf[8];
#pragma unroll
  for (int kx = 0; kx < 8; ++kx) {
    float4v a = *(const float4v*)(xl + kx * 32);
    float4v b2 = *(const float4v*)(xl + kx * 32 + 4);
    short8 v;
    v[0] = f2bf(a[0]); v[1] = f2bf(a[1]); v[2] = f2bf(a[2]); v[3] = f2bf(a[3]);
    v[4] = f2bf(b2[0]); v[5] = f2bf(b2[1]); v[6] = f2bf(b2[2]); v[7] = f2bf(b2[3]);
    xf[kx] = v;
  }
  const short8* wf = (const short8*)wfrag;
#pragma unroll 1
  for (int cb = 0; cb < 32; ++cb) {
#pragma unroll
    for (int g = 0; g < 3; ++g) {
      const float* bias = (g == 0) ? bz : ((g == 1) ? br : bh);
      float bv = bias[cb * 16 + l15];
      float4v acc = {bv, bv, bv, bv};
#pragma unroll
      for (int kx = 0; kx < 8; ++kx)
        acc = mfma_bf16(xf[kx], wf[((cb * 3 + g) * 24 + 16 + kx) * 64 + l], acc);
#pragma unroll
      for (int i = 0; i < 4; ++i)
        xp[(row0 + lhi * 4 + i) * HX + g * 512 + cb * 16 + l15] = f2bf(acc[i]);
    }
  }
}

// ---- per-wave flag barrier (XCD-L2-resident, no RMW, no syncthreads) ----
__device__ __forceinline__ void arrive_flag(int* fl, int wid, int val) {
  asm volatile("s_waitcnt vmcnt(0)" ::: "memory");  // data stores acked in L2
  if ((threadIdx.x & 63) == 0)
    __hip_atomic_store(fl + wid, val, __ATOMIC_RELAXED, __HIP_MEMORY_SCOPE_AGENT);
}
__device__ __forceinline__ void wait_flags(const int* fl, int tgt) {
  const int* p = fl + ((threadIdx.x & 63) & 31);
  for (;;) {
    int v = __hip_atomic_load(p, __ATOMIC_RELAXED, __HIP_MEMORY_SCOPE_AGENT);
    if (!__any(v < tgt)) break;
  }
}

// sc0 (L1-bypass) 16B fragment load from XCD L2
__device__ __forceinline__ short8 ld_frag(const short* p) {
  const u64* q = (const u64*)p;
  u64 lo = __hip_atomic_load(q, __ATOMIC_RELAXED, __HIP_MEMORY_SCOPE_AGENT);
  u64 hi = __hip_atomic_load(q + 1, __ATOMIC_RELAXED, __HIP_MEMORY_SCOPE_AGENT);
  short4v l4 = __builtin_bit_cast(short4v, lo);
  short4v h4 = __builtin_bit_cast(short4v, hi);
  return __builtin_shufflevector(l4, h4, 0, 1, 2, 3, 4, 5, 6, 7);
}

// ---- phase helpers ----
__device__ __forceinline__ void gate_phase1(const short* hb_lane,
    const short8* wz, const short8* wr, float4v azx, float4v arx,
    float bz, float br, float4v& z, float4v& rr) {
  float4v az = azx, ar = arx;
#pragma unroll
  for (int kk = 0; kk < 16; ++kk) {
    short8 a = ld_frag(hb_lane + kk * 32);
    az = mfma_bf16(a, wz[kk], az);
    ar = mfma_bf16(a, wr[kk], ar);
  }
#pragma unroll
  for (int i = 0; i < 4; ++i) {
    z[i] = sigm(az[i] + bz);
    rr[i] = sigm(ar[i] + br);
  }
}
__device__ __forceinline__ float4v gate_phase2(const short* rh_lane,
    const short8* wh, float4v ahx, float bh, float4v z, float4v h_loc) {
  float4v ah = ahx;
#pragma unroll
  for (int kk = 0; kk < 16; ++kk) {
    short8 a = ld_frag(rh_lane + kk * 32);
    ah = mfma_bf16(a, wh[kk], ah);
  }
  float4v hn;
#pragma unroll
  for (int i = 0; i < 4; ++i) {
    float hv = tanh_(ah[i] + bh);
    hn[i] = (1.0f - z[i]) * h_loc[i] + z[i] * hv;
  }
  return hn;
}

template <bool XB>
__device__ __forceinline__ void load_xf(short8 (&xf)[8], const short* xb_l,
                                        const float* xf_l, int t) {
#pragma unroll
  for (int kx = 0; kx < 8; ++kx) {
    if constexpr (XB) {
      xf[kx] = *(const short8*)(xb_l + (size_t)t * FF + kx * 32);
    } else {
      const float* xl = xf_l + (size_t)t * FF;
      float4v a = *(const float4v*)(xl + kx * 32);
      float4v b2 = *(const float4v*)(xl + kx * 32 + 4);
      short8 v;
      v[0] = f2bf(a[0]); v[1] = f2bf(a[1]); v[2] = f2bf(a[2]); v[3] = f2bf(a[3]);
      v[4] = f2bf(b2[0]); v[5] = f2bf(b2[1]); v[6] = f2bf(b2[2]); v[7] = f2bf(b2[3]);
      xf[kx] = v;
    }
  }
}
__device__ __forceinline__ void prime_x(const short8 (&xf)[8],
    const short8* wz, const short8* wr, const short8* wh,
    float4v& azx, float4v& arx, float4v& ahx) {
  azx = (float4v){0.f, 0.f, 0.f, 0.f};
  arx = (float4v){0.f, 0.f, 0.f, 0.f};
  ahx = (float4v){0.f, 0.f, 0.f, 0.f};
#pragma unroll
  for (int kx = 0; kx < 8; ++kx) {
    azx = mfma_bf16(xf[kx], wz[16 + kx], azx);
    arx = mfma_bf16(xf[kx], wr[16 + kx], arx);
    ahx = mfma_bf16(xf[kx], wh[16 + kx], ahx);
  }
}

// XM: 2 = xproj (bf16 precomputed projections), 1 = xb bf16 in-loop, 0 = f32 x in-loop
template <int XM>
__global__ __launch_bounds__(256, 1) void gru_kernel(
    const void* __restrict__ xv, const short* __restrict__ wfrag,
    short* __restrict__ hbuf, short* __restrict__ rhbuf,
    float* __restrict__ hfin, int* __restrict__ ctrl,
    const float* __restrict__ bzv, const float* __restrict__ brv,
    const float* __restrict__ bhv) {
  // ---- claim a slot in this XCD (8 workers per XCD) ----
  __shared__ int s_slot, s_xcc;
  if (threadIdx.x == 0) {
    unsigned xcc;
    asm volatile("s_getreg_b32 %0, hwreg(HW_REG_XCC_ID)" : "=s"(xcc));
    xcc &= 7u;
    s_xcc = (int)xcc;
    s_slot = atomicAdd(ctrl + xcc * 16, 1);
  }
  __syncthreads();
  const int slot = s_slot;
  if (slot >= GROUP_WGS) return;
  const int group = s_xcc;
  const int member = slot;

  const int tid = threadIdx.x;
  const int w = tid >> 6;
  const int l = tid & 63;
  const int l15 = l & 15;
  const int lhi = l >> 4;
  const int cbg = member * 4 + w;              // wave id in group == 16-col block
  const int jc = cbg * 16;
  const int rbA = group * 32;
  const int rbB = rbA + 16;

  // ---- weights -> registers (h-part only for XM==2) ----
  constexpr int NW = (XM == 2) ? 16 : 24;
  const short8* wf = (const short8*)wfrag;
  short8 wz[NW], wr[NW], wh[NW];
#pragma unroll
  for (int kk = 0; kk < NW; ++kk) wz[kk] = wf[((cbg * 3 + 0) * 24 + kk) * 64 + l];
#pragma unroll
  for (int kk = 0; kk < NW; ++kk) wr[kk] = wf[((cbg * 3 + 1) * 24 + kk) * 64 + l];
#pragma unroll
  for (int kk = 0; kk < NW; ++kk) wh[kk] = wf[((cbg * 3 + 2) * 24 + kk) * 64 + l];

  // biases: folded into xproj in XM==2
  const float bz = (XM == 2) ? 0.f : bzv[jc + l15];
  const float br = (XM == 2) ? 0.f : brv[jc + l15];
  const float bh = (XM == 2) ? 0.f : bhv[jc + l15];

  const int drowA = rbA + lhi * 4, drowB = rbB + lhi * 4;
  const int dcol = jc + l15;

  const short* hbA = hbuf + (size_t)(rbA + l15) * HH + lhi * 8;
  const short* hbB = hbuf + (size_t)(rbB + l15) * HH + lhi * 8;
  const short* rhA = rhbuf + (size_t)(rbA + l15) * HH + lhi * 8;
  const short* rhB = rhbuf + (size_t)(rbB + l15) * HH + lhi * 8;

  // mode-specific x pointers
  const float* xfA32 = (XM == 0) ? ((const float*)xv + (size_t)(rbA + l15) * TT * FF + lhi * 8) : nullptr;
  const float* xfB32 = (XM == 0) ? ((const float*)xv + (size_t)(rbB + l15) * TT * FF + lhi * 8) : nullptr;
  const short* xbA = (XM == 1) ? ((const short*)xv + (size_t)(rbA + l15) * TT * FF + lhi * 8) : nullptr;
  const short* xbB = (XM == 1) ? ((const short*)xv + (size_t)(rbB + l15) * TT * FF + lhi * 8) : nullptr;
  // xproj row bases (XM==2): lane reads rows drow+i at col dcol, gates *512
  const short* xpA[4];
  const short* xpB[4];
  if constexpr (XM == 2) {
    const short* xp = (const short*)xv;
#pragma unroll
    for (int i = 0; i < 4; ++i) {
      xpA[i] = xp + (size_t)(drowA + i) * TT * HX + dcol;
      xpB[i] = xp + (size_t)(drowB + i) * TT * HX + dcol;
    }
  }

  float4v h_locA = {0.f, 0.f, 0.f, 0.f}, h_locB = {0.f, 0.f, 0.f, 0.f};
  int* fb = ctrl + 256 + group * 128;          // per-group flag block (ints)
  int* rhAf = fb, * rhBf = fb + 32, * hAf = fb + 64, * hBf = fb + 96;

  // x-contribution accumulators (init for t=0)
  float4v azxA, arxA, ahxA, azxB, arxB, ahxB;
  unsigned short nzA[4], nrA[4], nhA[4], nzB[4], nrB[4], nhB[4];
  if constexpr (XM == 2) {
#pragma unroll
    for (int i = 0; i < 4; ++i) {
      azxA[i] = bf2f(xpA[i][0]); arxA[i] = bf2f(xpA[i][512]); ahxA[i] = bf2f(xpA[i][1024]);
      azxB[i] = bf2f(xpB[i][0]); arxB[i] = bf2f(xpB[i][512]); ahxB[i] = bf2f(xpB[i][1024]);
    }
  } else {
    short8 xf[8];
    load_xf<XM == 1>(xf, xbA, xfA32, 0);
    prime_x(xf, wz, wr, wh, azxA, arxA, ahxA);
    load_xf<XM == 1>(xf, xbB, xfB32, 0);
    prime_x(xf, wz, wr, wh, azxB, arxB, ahxB);
  }

#pragma unroll 1
  for (int t = 0; t < TT; ++t) {
    // ===== P1A: z,r set A =====
    if (t) wait_flags(hAf, t);
    float4v zA, rrA;
    gate_phase1(hbA, wz, wr, azxA, arxA, bz, br, zA, rrA);
#pragma unroll
    for (int i = 0; i < 4; ++i)
      rhbuf[(size_t)(drowA + i) * HH + dcol] = f2bf(rrA[i] * h_locA[i]);
    arrive_flag(rhAf, cbg, t + 1);

    // ===== P1B =====
    if (t) wait_flags(hBf, t);
    float4v zB, rrB;
    gate_phase1(hbB, wz, wr, azxB, arxB, bz, br, zB, rrB);
#pragma unroll
    for (int i = 0; i < 4; ++i)
      rhbuf[(size_t)(drowB + i) * HH + dcol] = f2bf(rrB[i] * h_locB[i]);
    arrive_flag(rhBf, cbg, t + 1);

    // prefetch xproj(t+1): issued here, lands during P2s (XM==2 only)
    if (XM == 2 && t + 1 < TT) {
      size_t toff = (size_t)(t + 1) * HX;
#pragma unroll
      for (int i = 0; i < 4; ++i) {
        nzA[i] = *(const unsigned short*)(xpA[i] + toff);
        nrA[i] = *(const unsigned short*)(xpA[i] + toff + 512);
        nhA[i] = *(const unsigned short*)(xpA[i] + toff + 1024);
        nzB[i] = *(const unsigned short*)(xpB[i] + toff);
        nrB[i] = *(const unsigned short*)(xpB[i] + toff + 512);
        nhB[i] = *(const unsigned short*)(xpB[i] + toff + 1024);
      }
    }

    // ===== P2A: h_tilde + update =====
    wait_flags(rhAf, t + 1);
    h_locA = gate_phase2(rhA, wh, ahxA, bh, zA, h_locA);
    if (t + 1 < TT) {
#pragma unroll
      for (int i = 0; i < 4; ++i)
        hbuf[(size_t)(drowA + i) * HH + dcol] = f2bf(h_locA[i]);
      arrive_flag(hAf, cbg, t + 1);
    } else {
#pragma unroll
      for (int i = 0; i < 4; ++i)
        hfin[(size_t)(drowA + i) * HH + dcol] = h_locA[i];
    }

    // ===== P2B =====
    wait_flags(rhBf, t + 1);
    h_locB = gate_phase2(rhB, wh, ahxB, bh, zB, h_locB);
    if (t + 1 < TT) {
#pragma unroll
      for (int i = 0; i < 4; ++i)
        hbuf[(size_t)(drowB + i) * HH + dcol] = f2bf(h_locB[i]);
      arrive_flag(hBf, cbg, t + 1);
    } else {
#pragma unroll
      for (int i = 0; i < 4; ++i)
        hfin[(size_t)(drowB + i) * HH + dcol] = h_locB[i];
    }

    // ===== next-step x contributions =====
    if (t + 1 < TT) {
      if constexpr (XM == 2) {
#pragma unroll
        for (int i = 0; i < 4; ++i) {
          azxA[i] = bf2f(nzA[i]); arxA[i] = bf2f(nrA[i]); ahxA[i] = bf2f(nhA[i]);
          azxB[i] = bf2f(nzB[i]); arxB[i] = bf2f(nrB[i]); ahxB[i] = bf2f(nhB[i]);
        }
      } else {
        short8 xf[8];
        load_xf<XM == 1>(xf, xbA, xfA32, t + 1);
        prime_x(xf, wz, wr, wh, azxA, arxA, ahxA);
        load_xf<XM == 1>(xf, xbB, xfB32, t + 1);
        prime_x(xf, wz, wr, wh, azxB, arxB, ahxB);
      }
    }
  }
}

// out[b, c] = h_final[b,:] @ fc_w[:,c] + fc_b[c]
__global__ void fc_kernel(const float* __restrict__ hfin, const float* __restrict__ fw,
                          const float* __restrict__ fb, float* __restrict__ out) {
  int b = blockIdx.x;
  int tid = threadIdx.x;  // 64
  float p[10];
#pragma unroll
  for (int c = 0; c < 10; ++c) p[c] = 0.f;
  for (int k = tid; k < HH; k += 64) {
    float hv = hfin[(size_t)b * HH + k];
#pragma unroll
    for (int c = 0; c < 10; ++c) p[c] += hv * fw[k * 10 + c];
  }
#pragma unroll
  for (int c = 0; c < 10; ++c) {
    float v = p[c];
    for (int off = 32; off > 0; off >>= 1) v += __shfl_down(v, off);
    if (tid == 0) out[b * 10 + c] = v + fb[c];
  }
}

extern "C" void kernel_launch(void* const* d_in, const int* in_sizes, int n_in,
                              void* d_out, int out_size, void* d_ws, size_t ws_size,
                              hipStream_t stream) {
  const float* x = (const float*)d_in[0];
  const float* Wz_w = (const float*)d_in[1];
  const float* Wz_b = (const float*)d_in[2];
  const float* Wr_w = (const float*)d_in[3];
  const float* Wr_b = (const float*)d_in[4];
  const float* Wh_w = (const float*)d_in[5];
  const float* Wh_b = (const float*)d_in[6];
  const float* fc_w = (const float*)d_in[7];
  const float* fc_b = (const float*)d_in[8];

  char* ws = (char*)d_ws;
  short* wfrag = (short*)(ws + WFRAG_OFF);
  short* hbuf = (short*)(ws + HBUF_OFF);
  short* rhbuf = (short*)(ws + RHBUF_OFF);
  float* hfin = (float*)(ws + HFIN_OFF);
  int* ctrl = (int*)(ws + CTRL_OFF);
  short* xbase = (short*)(ws + XBASE_OFF);

  // h0 = 0, claim + flag arrays = 0 (EVERY launch)
  hipMemsetAsync(hbuf, 0, BB * HH * 2, stream);
  hipMemsetAsync(ctrl, 0, CTRL_BYTES, stream);

  prep_w<<<576, 256, 0, stream>>>(Wz_w, Wr_w, Wh_w, wfrag);

  if (ws_size >= WS_M2) {
    xproj_gemm<<<BB * TT / 64, 256, 0, stream>>>(x, wfrag, Wz_b, Wr_b, Wh_b, xbase);
    gru_kernel<2><<<256, 256, 0, stream>>>(xbase, wfrag, hbuf, rhbuf, hfin, ctrl,
                                           Wz_b, Wr_b, Wh_b);
  } else if (ws_size >= WS_M1) {
    xprep<<<(BB * TT * FF / 8) / 256, 256, 0, stream>>>(x, xbase);
    gru_kernel<1><<<256, 256, 0, stream>>>(xbase, wfrag, hbuf, rhbuf, hfin, ctrl,
                                           Wz_b, Wr_b, Wh_b);
  } else {
    gru_kernel<0><<<256, 256, 0, stream>>>(x, wfrag, hbuf, rhbuf, hfin, ctrl,
                                           Wz_b, Wr_b, Wh_b);
  }
  fc_kernel<<<BB, 64, 0, stream>>>(hfin, fc_w, fc_b, (float*)d_out);
}

// Round 8
// 9140.659 us; speedup vs baseline: 1.1663x; 1.0136x over previous
//
#include <hip/hip_runtime.h>

// GRU: B=256, T=512, F=256, H=512, C=10  (MI355X / gfx950)
// Round 8 = Round 5 (proven correct, 9.26ms) with ONE change: the 16 h/rh
// fragment loads per phase are BATCHED into a register array before the MFMA
// loop. R3-R5 loaded inside the MFMA loop -> 16 serialized ~600-900cy
// agent-scope round trips = the invariant ~4.4us/phase. Batched relaxed
// atomic loads issue back-to-back -> ONE round trip per phase.
// Topology: xproj precomputed; 8 XCD-local groups x 32 rows (A/B ping-pong)
// x 8 WGs x 4 waves x 16 cols; h-part weights in registers; per-wave flag
// barriers (agent-scope HIP atomics -- the safe, proven path).

#define BB 256
#define TT 512
#define FF 256
#define HH 512
#define HX 1536
#define GROUP_WGS 8

typedef short short8 __attribute__((ext_vector_type(8)));
typedef short short4v __attribute__((ext_vector_type(4)));
typedef float float4v __attribute__((ext_vector_type(4)));
typedef unsigned long long u64;

// ws layout (bytes)
#define WFRAG_OFF 0
#define WFRAG_BYTES (32 * 3 * 24 * 64 * 8 * 2)            // 2,359,296
#define HBUF_OFF (WFRAG_OFF + WFRAG_BYTES)                 // bf16 h   [256][512]
#define RHBUF_OFF (HBUF_OFF + BB * HH * 2)                 // bf16 r*h [256][512]
#define HFIN_OFF (RHBUF_OFF + BB * HH * 2)                 // f32 h_final
#define CTRL_OFF (HFIN_OFF + BB * HH * 4)                  // claims + flags
#define CTRL_BYTES 16384
#define XBASE_OFF (CTRL_OFF + CTRL_BYTES)
#define XB_BYTES ((size_t)BB * TT * FF * 2)                // 67 MB (mode 1)
#define XPROJ_BYTES ((size_t)BB * TT * HX * 2)             // 402 MB (mode 2)
#define WS_M2 ((size_t)XBASE_OFF + XPROJ_BYTES)
#define WS_M1 ((size_t)XBASE_OFF + XB_BYTES)

__device__ __forceinline__ short f2bf(float f) {
  unsigned u = __builtin_bit_cast(unsigned, f);
  u += 0x7fffu + ((u >> 16) & 1u);            // RNE to bf16
  return (short)(u >> 16);
}
__device__ __forceinline__ float bf2f(unsigned short u) {
  return __builtin_bit_cast(float, (unsigned)u << 16);
}
__device__ __forceinline__ float sigm(float v) { return 1.0f / (1.0f + __expf(-v)); }
__device__ __forceinline__ float tanh_(float v) { return 2.0f / (1.0f + __expf(-2.0f * v)) - 1.0f; }
__device__ __forceinline__ float4v mfma_bf16(short8 a, short8 b, float4v c) {
  return __builtin_amdgcn_mfma_f32_16x16x32_bf16(a, b, c, 0, 0, 0);
}

// ---- weight prep: f32 [768][512] -> bf16 MFMA B-fragments ----
__global__ void prep_w(const float* __restrict__ Wz, const float* __restrict__ Wr,
                       const float* __restrict__ Wh, short* __restrict__ wfrag) {
  int id = blockIdx.x * 256 + threadIdx.x;     // 576*256 == 32*3*24*64
  int lane = id & 63;
  int rest = id >> 6;
  int kk = rest % 24;
  int gc = rest / 24;
  int g = gc % 3;
  int cb = gc / 3;
  if (cb >= 32) return;
  const float* W = (g == 0) ? Wz : ((g == 1) ? Wr : Wh);
  int n = cb * 16 + (lane & 15);
  int kbase = kk * 32 + (lane >> 4) * 8;
  short8 v;
#pragma unroll
  for (int j = 0; j < 8; ++j) v[j] = f2bf(W[(size_t)(kbase + j) * HH + n]);
  *(((short8*)wfrag) + id) = v;
}

// ---- x prep (mode 1 fallback): f32 -> bf16 ----
__global__ void xprep(const float* __restrict__ x, short* __restrict__ xb) {
  size_t i = (size_t)blockIdx.x * 256 + threadIdx.x;
  const float4v* src = (const float4v*)x;
  float4v a = src[i * 2], b = src[i * 2 + 1];
  short8 v;
  v[0] = f2bf(a[0]); v[1] = f2bf(a[1]); v[2] = f2bf(a[2]); v[3] = f2bf(a[3]);
  v[4] = f2bf(b[0]); v[5] = f2bf(b[1]); v[6] = f2bf(b[2]); v[7] = f2bf(b[3]);
  *(((short8*)xb) + i) = v;
}

// ---- xproj GEMM (mode 2): [BT,256] @ x-part weights -> bf16 [BT][3*512], bias folded ----
__global__ __launch_bounds__(256) void xproj_gemm(
    const float* __restrict__ x, const short* __restrict__ wfrag,
    const float* __restrict__ bz, const float* __restrict__ br,
    const float* __restrict__ bh, short* __restrict__ xp) {
  const int w = threadIdx.x >> 6, l = threadIdx.x & 63;
  const int l15 = l & 15, lhi = l >> 4;
  const size_t row0 = (size_t)blockIdx.x * 64 + w * 16;
  const float* xl = x + (row0 + l15) * FF + lhi * 8;
  short8 xf[8];
#pragma unroll
  for (int kx = 0; kx < 8; ++kx) {
    float4v a = *(const float4v*)(xl + kx * 32);
    float4v b2 = *(const float4v*)(xl + kx * 32 + 4);
    short8 v;
    v[0] = f2bf(a[0]); v[1] = f2bf(a[1]); v[2] = f2bf(a[2]); v[3] = f2bf(a[3]);
    v[4] = f2bf(b2[0]); v[5] = f2bf(b2[1]); v[6] = f2bf(b2[2]); v[7] = f2bf(b2[3]);
    xf[kx] = v;
  }
  const short8* wf = (const short8*)wfrag;
#pragma unroll 1
  for (int cb = 0; cb < 32; ++cb) {
#pragma unroll
    for (int g = 0; g < 3; ++g) {
      const float* bias = (g == 0) ? bz : ((g == 1) ? br : bh);
      float bv = bias[cb * 16 + l15];
      float4v acc = {bv, bv, bv, bv};
#pragma unroll
      for (int kx = 0; kx < 8; ++kx)
        acc = mfma_bf16(xf[kx], wf[((cb * 3 + g) * 24 + 16 + kx) * 64 + l], acc);
#pragma unroll
      for (int i = 0; i < 4; ++i)
        xp[(row0 + lhi * 4 + i) * HX + g * 512 + cb * 16 + l15] = f2bf(acc[i]);
    }
  }
}

// ---- per-wave flag barrier (agent-scope atomics: proven correct) ----
__device__ __forceinline__ void arrive_flag(int* fl, int wid, int val) {
  asm volatile("s_waitcnt vmcnt(0)" ::: "memory");  // data stores complete first
  if ((threadIdx.x & 63) == 0)
    __hip_atomic_store(fl + wid, val, __ATOMIC_RELAXED, __HIP_MEMORY_SCOPE_AGENT);
}
__device__ __forceinline__ void wait_flags(const int* fl, int tgt) {
  const int* p = fl + (threadIdx.x & 31);
  for (;;) {
    int v = __hip_atomic_load(p, __ATOMIC_RELAXED, __HIP_MEMORY_SCOPE_AGENT);
    if (!__any(v < tgt)) break;
  }
}

// L1-bypassing 16B fragment load (two relaxed agent-scope u64 loads)
__device__ __forceinline__ short8 ld_frag(const short* p) {
  const u64* q = (const u64*)p;
  u64 lo = __hip_atomic_load(q, __ATOMIC_RELAXED, __HIP_MEMORY_SCOPE_AGENT);
  u64 hi = __hip_atomic_load(q + 1, __ATOMIC_RELAXED, __HIP_MEMORY_SCOPE_AGENT);
  short4v l4 = __builtin_bit_cast(short4v, lo);
  short4v h4 = __builtin_bit_cast(short4v, hi);
  return __builtin_shufflevector(l4, h4, 0, 1, 2, 3, 4, 5, 6, 7);
}

// ---- phase helpers: BATCHED loads (one round trip), then MFMA ----
__device__ __forceinline__ void gate_phase1(const short* hb_lane,
    const short8* wz, const short8* wr, float4v azx, float4v arx,
    float bz, float br, float4v& z, float4v& rr) {
  short8 a[16];
#pragma unroll
  for (int kk = 0; kk < 16; ++kk) a[kk] = ld_frag(hb_lane + kk * 32);
  float4v az = azx, ar = arx;
#pragma unroll
  for (int kk = 0; kk < 16; ++kk) {
    az = mfma_bf16(a[kk], wz[kk], az);
    ar = mfma_bf16(a[kk], wr[kk], ar);
  }
#pragma unroll
  for (int i = 0; i < 4; ++i) {
    z[i] = sigm(az[i] + bz);
    rr[i] = sigm(ar[i] + br);
  }
}
__device__ __forceinline__ float4v gate_phase2(const short* rh_lane,
    const short8* wh, float4v ahx, float bh, float4v z, float4v h_loc) {
  short8 a[16];
#pragma unroll
  for (int kk = 0; kk < 16; ++kk) a[kk] = ld_frag(rh_lane + kk * 32);
  float4v ah = ahx;
#pragma unroll
  for (int kk = 0; kk < 16; ++kk)
    ah = mfma_bf16(a[kk], wh[kk], ah);
  float4v hn;
#pragma unroll
  for (int i = 0; i < 4; ++i) {
    float hv = tanh_(ah[i] + bh);
    hn[i] = (1.0f - z[i]) * h_loc[i] + z[i] * hv;
  }
  return hn;
}

template <bool XB>
__device__ __forceinline__ void load_xf(short8 (&xf)[8], const short* xb_l,
                                        const float* xf_l, int t) {
#pragma unroll
  for (int kx = 0; kx < 8; ++kx) {
    if constexpr (XB) {
      xf[kx] = *(const short8*)(xb_l + (size_t)t * FF + kx * 32);
    } else {
      const float* xl = xf_l + (size_t)t * FF;
      float4v a = *(const float4v*)(xl + kx * 32);
      float4v b2 = *(const float4v*)(xl + kx * 32 + 4);
      short8 v;
      v[0] = f2bf(a[0]); v[1] = f2bf(a[1]); v[2] = f2bf(a[2]); v[3] = f2bf(a[3]);
      v[4] = f2bf(b2[0]); v[5] = f2bf(b2[1]); v[6] = f2bf(b2[2]); v[7] = f2bf(b2[3]);
      xf[kx] = v;
    }
  }
}
__device__ __forceinline__ void prime_x(const short8 (&xf)[8],
    const short8* wz, const short8* wr, const short8* wh,
    float4v& azx, float4v& arx, float4v& ahx) {
  azx = (float4v){0.f, 0.f, 0.f, 0.f};
  arx = (float4v){0.f, 0.f, 0.f, 0.f};
  ahx = (float4v){0.f, 0.f, 0.f, 0.f};
#pragma unroll
  for (int kx = 0; kx < 8; ++kx) {
    azx = mfma_bf16(xf[kx], wz[16 + kx], azx);
    arx = mfma_bf16(xf[kx], wr[16 + kx], arx);
    ahx = mfma_bf16(xf[kx], wh[16 + kx], ahx);
  }
}

// XM: 2 = xproj precomputed, 1 = xb bf16 in-loop, 0 = f32 x in-loop
template <int XM>
__global__ __launch_bounds__(256, 1) void gru_kernel(
    const void* __restrict__ xv, const short* __restrict__ wfrag,
    short* __restrict__ hbuf, short* __restrict__ rhbuf,
    float* __restrict__ hfin, int* __restrict__ ctrl,
    const float* __restrict__ bzv, const float* __restrict__ brv,
    const float* __restrict__ bhv) {
  // ---- claim a slot in this XCD (8 workers per XCD) ----
  __shared__ int s_slot, s_xcc;
  if (threadIdx.x == 0) {
    unsigned xcc;
    asm volatile("s_getreg_b32 %0, hwreg(HW_REG_XCC_ID)" : "=s"(xcc));
    xcc &= 7u;
    s_xcc = (int)xcc;
    s_slot = atomicAdd(ctrl + xcc * 16, 1);
  }
  __syncthreads();
  const int slot = s_slot;
  if (slot >= GROUP_WGS) return;
  const int group = s_xcc;
  const int member = slot;

  const int tid = threadIdx.x;
  const int w = tid >> 6;
  const int l = tid & 63;
  const int l15 = l & 15;
  const int lhi = l >> 4;
  const int cbg = member * 4 + w;              // wave id in group == 16-col block
  const int jc = cbg * 16;
  const int rbA = group * 32;
  const int rbB = rbA + 16;

  // ---- weights -> registers (h-part only for XM==2) ----
  constexpr int NW = (XM == 2) ? 16 : 24;
  const short8* wf = (const short8*)wfrag;
  short8 wz[NW], wr[NW], wh[NW];
#pragma unroll
  for (int kk = 0; kk < NW; ++kk) wz[kk] = wf[((cbg * 3 + 0) * 24 + kk) * 64 + l];
#pragma unroll
  for (int kk = 0; kk < NW; ++kk) wr[kk] = wf[((cbg * 3 + 1) * 24 + kk) * 64 + l];
#pragma unroll
  for (int kk = 0; kk < NW; ++kk) wh[kk] = wf[((cbg * 3 + 2) * 24 + kk) * 64 + l];

  const float bz = (XM == 2) ? 0.f : bzv[jc + l15];
  const float br = (XM == 2) ? 0.f : brv[jc + l15];
  const float bh = (XM == 2) ? 0.f : bhv[jc + l15];

  const int drowA = rbA + lhi * 4, drowB = rbB + lhi * 4;
  const int dcol = jc + l15;

  const short* hbA = hbuf + (size_t)(rbA + l15) * HH + lhi * 8;
  const short* hbB = hbuf + (size_t)(rbB + l15) * HH + lhi * 8;
  const short* rhA = rhbuf + (size_t)(rbA + l15) * HH + lhi * 8;
  const short* rhB = rhbuf + (size_t)(rbB + l15) * HH + lhi * 8;

  const float* xfA32 = (XM == 0) ? ((const float*)xv + (size_t)(rbA + l15) * TT * FF + lhi * 8) : nullptr;
  const float* xfB32 = (XM == 0) ? ((const float*)xv + (size_t)(rbB + l15) * TT * FF + lhi * 8) : nullptr;
  const short* xbA = (XM == 1) ? ((const short*)xv + (size_t)(rbA + l15) * TT * FF + lhi * 8) : nullptr;
  const short* xbB = (XM == 1) ? ((const short*)xv + (size_t)(rbB + l15) * TT * FF + lhi * 8) : nullptr;
  const short* xpA[4];
  const short* xpB[4];
  if constexpr (XM == 2) {
    const short* xp = (const short*)xv;
#pragma unroll
    for (int i = 0; i < 4; ++i) {
      xpA[i] = xp + (size_t)(drowA + i) * TT * HX + dcol;
      xpB[i] = xp + (size_t)(drowB + i) * TT * HX + dcol;
    }
  }

  float4v h_locA = {0.f, 0.f, 0.f, 0.f}, h_locB = {0.f, 0.f, 0.f, 0.f};
  int* fb = ctrl + 256 + group * 128;
  int* rhAf = fb, * rhBf = fb + 32, * hAf = fb + 64, * hBf = fb + 96;

  float4v azxA, arxA, ahxA, azxB, arxB, ahxB;
  unsigned short nzA[4], nrA[4], nhA[4], nzB[4], nrB[4], nhB[4];
  if constexpr (XM == 2) {
#pragma unroll
    for (int i = 0; i < 4; ++i) {
      azxA[i] = bf2f(xpA[i][0]); arxA[i] = bf2f(xpA[i][512]); ahxA[i] = bf2f(xpA[i][1024]);
      azxB[i] = bf2f(xpB[i][0]); arxB[i] = bf2f(xpB[i][512]); ahxB[i] = bf2f(xpB[i][1024]);
    }
  } else {
    short8 xf[8];
    load_xf<XM == 1>(xf, xbA, xfA32, 0);
    prime_x(xf, wz, wr, wh, azxA, arxA, ahxA);
    load_xf<XM == 1>(xf, xbB, xfB32, 0);
    prime_x(xf, wz, wr, wh, azxB, arxB, ahxB);
  }

#pragma unroll 1
  for (int t = 0; t < TT; ++t) {
    // ===== P1A: z,r set A =====
    if (t) wait_flags(hAf, t);
    float4v zA, rrA;
    gate_phase1(hbA, wz, wr, azxA, arxA, bz, br, zA, rrA);
#pragma unroll
    for (int i = 0; i < 4; ++i)
      rhbuf[(size_t)(drowA + i) * HH + dcol] = f2bf(rrA[i] * h_locA[i]);
    arrive_flag(rhAf, cbg, t + 1);

    // ===== P1B =====
    if (t) wait_flags(hBf, t);
    float4v zB, rrB;
    gate_phase1(hbB, wz, wr, azxB, arxB, bz, br, zB, rrB);
#pragma unroll
    for (int i = 0; i < 4; ++i)
      rhbuf[(size_t)(drowB + i) * HH + dcol] = f2bf(rrB[i] * h_locB[i]);
    arrive_flag(rhBf, cbg, t + 1);

    // prefetch xproj(t+1): lands during P2s (XM==2 only)
    if (XM == 2 && t + 1 < TT) {
      size_t toff = (size_t)(t + 1) * HX;
#pragma unroll
      for (int i = 0; i < 4; ++i) {
        nzA[i] = *(const unsigned short*)(xpA[i] + toff);
        nrA[i] = *(const unsigned short*)(xpA[i] + toff + 512);
        nhA[i] = *(const unsigned short*)(xpA[i] + toff + 1024);
        nzB[i] = *(const unsigned short*)(xpB[i] + toff);
        nrB[i] = *(const unsigned short*)(xpB[i] + toff + 512);
        nhB[i] = *(const unsigned short*)(xpB[i] + toff + 1024);
      }
    }

    // ===== P2A: h_tilde + update =====
    wait_flags(rhAf, t + 1);
    h_locA = gate_phase2(rhA, wh, ahxA, bh, zA, h_locA);
    if (t + 1 < TT) {
#pragma unroll
      for (int i = 0; i < 4; ++i)
        hbuf[(size_t)(drowA + i) * HH + dcol] = f2bf(h_locA[i]);
      arrive_flag(hAf, cbg, t + 1);
    } else {
#pragma unroll
      for (int i = 0; i < 4; ++i)
        hfin[(size_t)(drowA + i) * HH + dcol] = h_locA[i];
    }

    // ===== P2B =====
    wait_flags(rhBf, t + 1);
    h_locB = gate_phase2(rhB, wh, ahxB, bh, zB, h_locB);
    if (t + 1 < TT) {
#pragma unroll
      for (int i = 0; i < 4; ++i)
        hbuf[(size_t)(drowB + i) * HH + dcol] = f2bf(h_locB[i]);
      arrive_flag(hBf, cbg, t + 1);
    } else {
#pragma unroll
      for (int i = 0; i < 4; ++i)
        hfin[(size_t)(drowB + i) * HH + dcol] = h_locB[i];
    }

    // ===== next-step x contributions =====
    if (t + 1 < TT) {
      if constexpr (XM == 2) {
#pragma unroll
        for (int i = 0; i < 4; ++i) {
          azxA[i] = bf2f(nzA[i]); arxA[i] = bf2f(nrA[i]); ahxA[i] = bf2f(nhA[i]);
          azxB[i] = bf2f(nzB[i]); arxB[i] = bf2f(nrB[i]); ahxB[i] = bf2f(nhB[i]);
        }
      } else {
        short8 xf[8];
        load_xf<XM == 1>(xf, xbA, xfA32, t + 1);
        prime_x(xf, wz, wr, wh, azxA, arxA, ahxA);
        load_xf<XM == 1>(xf, xbB, xfB32, t + 1);
        prime_x(xf, wz, wr, wh, azxB, arxB, ahxB);
      }
    }
  }
}

// out[b, c] = h_final[b,:] @ fc_w[:,c] + fc_b[c]
__global__ void fc_kernel(const float* __restrict__ hfin, const float* __restrict__ fw,
                          const float* __restrict__ fb, float* __restrict__ out) {
  int b = blockIdx.x;
  int tid = threadIdx.x;  // 64
  float p[10];
#pragma unroll
  for (int c = 0; c < 10; ++c) p[c] = 0.f;
  for (int k = tid; k < HH; k += 64) {
    float hv = hfin[(size_t)b * HH + k];
#pragma unroll
    for (int c = 0; c < 10; ++c) p[c] += hv * fw[k * 10 + c];
  }
#pragma unroll
  for (int c = 0; c < 10; ++c) {
    float v = p[c];
    for (int off = 32; off > 0; off >>= 1) v += __shfl_down(v, off);
    if (tid == 0) out[b * 10 + c] = v + fb[c];
  }
}

extern "C" void kernel_launch(void* const* d_in, const int* in_sizes, int n_in,
                              void* d_out, int out_size, void* d_ws, size_t ws_size,
                              hipStream_t stream) {
  const float* x = (const float*)d_in[0];
  const float* Wz_w = (const float*)d_in[1];
  const float* Wz_b = (const float*)d_in[2];
  const float* Wr_w = (const float*)d_in[3];
  const float* Wr_b = (const float*)d_in[4];
  const float* Wh_w = (const float*)d_in[5];
  const float* Wh_b = (const float*)d_in[6];
  const float* fc_w = (const float*)d_in[7];
  const float* fc_b = (const float*)d_in[8];

  char* ws = (char*)d_ws;
  short* wfrag = (short*)(ws + WFRAG_OFF);
  short* hbuf = (short*)(ws + HBUF_OFF);
  short* rhbuf = (short*)(ws + RHBUF_OFF);
  float* hfin = (float*)(ws + HFIN_OFF);
  int* ctrl = (int*)(ws + CTRL_OFF);
  short* xbase = (short*)(ws + XBASE_OFF);

  // h0 = 0, claim + flag arrays = 0 (EVERY launch)
  hipMemsetAsync(hbuf, 0, BB * HH * 2, stream);
  hipMemsetAsync(ctrl, 0, CTRL_BYTES, stream);

  prep_w<<<576, 256, 0, stream>>>(Wz_w, Wr_w, Wh_w, wfrag);

  if (ws_size >= WS_M2) {
    xproj_gemm<<<BB * TT / 64, 256, 0, stream>>>(x, wfrag, Wz_b, Wr_b, Wh_b, xbase);
    gru_kernel<2><<<256, 256, 0, stream>>>(xbase, wfrag, hbuf, rhbuf, hfin, ctrl,
                                           Wz_b, Wr_b, Wh_b);
  } else if (ws_size >= WS_M1) {
    xprep<<<(BB * TT * FF / 8) / 256, 256, 0, stream>>>(x, xbase);
    gru_kernel<1><<<256, 256, 0, stream>>>(xbase, wfrag, hbuf, rhbuf, hfin, ctrl,
                                           Wz_b, Wr_b, Wh_b);
  } else {
    gru_kernel<0><<<256, 256, 0, stream>>>(x, wfrag, hbuf, rhbuf, hfin, ctrl,
                                           Wz_b, Wr_b, Wh_b);
  }
  fc_kernel<<<BB, 64, 0, stream>>>(hfin, fc_w, fc_b, (float*)d_out);
}

// Round 9
// 4127.961 us; speedup vs baseline: 2.5826x; 2.2143x over previous
//
#include <hip/hip_runtime.h>

// GRU: B=256, T=512, F=256, H=512, C=10  (MI355X / gfx950)
// Round 9: (1) LDS tile staging -- each WG cooperatively loads the 16KB h/rh
// tile ONCE per phase (was 4x redundant per-wave LIC loads), XOR-swizzled LDS,
// ds_read_b128 fragments; 1-phase-ahead global prefetch. (2) "Burner" WGs:
// the 192 surplus WGs spin low-power dependent FMAs until a done-flag, keeping
// DPM clocks up (kernel is otherwise ~3% busy -> suspected heavy downclock).
// Topology unchanged: xproj precomputed; 8 XCD-local groups x 32 rows (A/B
// ping-pong) x 8 WGs x 4 waves x 16 cols; per-wave flag barriers.

#define BB 256
#define TT 512
#define FF 256
#define HH 512
#define HX 1536
#define GROUP_WGS 8

typedef short short8 __attribute__((ext_vector_type(8)));
typedef short short4v __attribute__((ext_vector_type(4)));
typedef float float4v __attribute__((ext_vector_type(4)));
typedef unsigned long long u64;

// ws layout (bytes)
#define WFRAG_OFF 0
#define WFRAG_BYTES (32 * 3 * 24 * 64 * 8 * 2)            // 2,359,296
#define HBUF_OFF (WFRAG_OFF + WFRAG_BYTES)                 // bf16 h   [256][512]
#define RHBUF_OFF (HBUF_OFF + BB * HH * 2)                 // bf16 r*h [256][512]
#define HFIN_OFF (RHBUF_OFF + BB * HH * 2)                 // f32 h_final
#define CTRL_OFF (HFIN_OFF + BB * HH * 4)                  // claims + done + flags
#define CTRL_BYTES 16384
#define XBASE_OFF (CTRL_OFF + CTRL_BYTES)
#define XB_BYTES ((size_t)BB * TT * FF * 2)                // 67 MB (mode 1)
#define XPROJ_BYTES ((size_t)BB * TT * HX * 2)             // 402 MB (mode 2)
#define WS_M2 ((size_t)XBASE_OFF + XPROJ_BYTES)
#define WS_M1 ((size_t)XBASE_OFF + XB_BYTES)

__device__ __forceinline__ short f2bf(float f) {
  unsigned u = __builtin_bit_cast(unsigned, f);
  u += 0x7fffu + ((u >> 16) & 1u);            // RNE to bf16
  return (short)(u >> 16);
}
__device__ __forceinline__ float bf2f(unsigned short u) {
  return __builtin_bit_cast(float, (unsigned)u << 16);
}
__device__ __forceinline__ float sigm(float v) { return 1.0f / (1.0f + __expf(-v)); }
__device__ __forceinline__ float tanh_(float v) { return 2.0f / (1.0f + __expf(-2.0f * v)) - 1.0f; }
__device__ __forceinline__ float4v mfma_bf16(short8 a, short8 b, float4v c) {
  return __builtin_amdgcn_mfma_f32_16x16x32_bf16(a, b, c, 0, 0, 0);
}

// ---- weight prep: f32 [768][512] -> bf16 MFMA B-fragments ----
__global__ void prep_w(const float* __restrict__ Wz, const float* __restrict__ Wr,
                       const float* __restrict__ Wh, short* __restrict__ wfrag) {
  int id = blockIdx.x * 256 + threadIdx.x;     // 576*256 == 32*3*24*64
  int lane = id & 63;
  int rest = id >> 6;
  int kk = rest % 24;
  int gc = rest / 24;
  int g = gc % 3;
  int cb = gc / 3;
  if (cb >= 32) return;
  const float* W = (g == 0) ? Wz : ((g == 1) ? Wr : Wh);
  int n = cb * 16 + (lane & 15);
  int kbase = kk * 32 + (lane >> 4) * 8;
  short8 v;
#pragma unroll
  for (int j = 0; j < 8; ++j) v[j] = f2bf(W[(size_t)(kbase + j) * HH + n]);
  *(((short8*)wfrag) + id) = v;
}

// ---- x prep (mode 1 fallback): f32 -> bf16 ----
__global__ void xprep(const float* __restrict__ x, short* __restrict__ xb) {
  size_t i = (size_t)blockIdx.x * 256 + threadIdx.x;
  const float4v* src = (const float4v*)x;
  float4v a = src[i * 2], b = src[i * 2 + 1];
  short8 v;
  v[0] = f2bf(a[0]); v[1] = f2bf(a[1]); v[2] = f2bf(a[2]); v[3] = f2bf(a[3]);
  v[4] = f2bf(b[0]); v[5] = f2bf(b[1]); v[6] = f2bf(b[2]); v[7] = f2bf(b[3]);
  *(((short8*)xb) + i) = v;
}

// ---- xproj GEMM (mode 2): [BT,256] @ x-part weights -> bf16 [BT][3*512], bias folded ----
__global__ __launch_bounds__(256) void xproj_gemm(
    const float* __restrict__ x, const short* __restrict__ wfrag,
    const float* __restrict__ bz, const float* __restrict__ br,
    const float* __restrict__ bh, short* __restrict__ xp) {
  const int w = threadIdx.x >> 6, l = threadIdx.x & 63;
  const int l15 = l & 15, lhi = l >> 4;
  const size_t row0 = (size_t)blockIdx.x * 64 + w * 16;
  const float* xl = x + (row0 + l15) * FF + lhi * 8;
  short8 xf[8];
#pragma unroll
  for (int kx = 0; kx < 8; ++kx) {
    float4v a = *(const float4v*)(xl + kx * 32);
    float4v b2 = *(const float4v*)(xl + kx * 32 + 4);
    short8 v;
    v[0] = f2bf(a[0]); v[1] = f2bf(a[1]); v[2] = f2bf(a[2]); v[3] = f2bf(a[3]);
    v[4] = f2bf(b2[0]); v[5] = f2bf(b2[1]); v[6] = f2bf(b2[2]); v[7] = f2bf(b2[3]);
    xf[kx] = v;
  }
  const short8* wf = (const short8*)wfrag;
#pragma unroll 1
  for (int cb = 0; cb < 32; ++cb) {
#pragma unroll
    for (int g = 0; g < 3; ++g) {
      const float* bias = (g == 0) ? bz : ((g == 1) ? br : bh);
      float bv = bias[cb * 16 + l15];
      float4v acc = {bv, bv, bv, bv};
#pragma unroll
      for (int kx = 0; kx < 8; ++kx)
        acc = mfma_bf16(xf[kx], wf[((cb * 3 + g) * 24 + 16 + kx) * 64 + l], acc);
#pragma unroll
      for (int i = 0; i < 4; ++i)
        xp[(row0 + lhi * 4 + i) * HX + g * 512 + cb * 16 + l15] = f2bf(acc[i]);
    }
  }
}

// ---- per-wave flag barrier (agent-scope atomics: proven correct) ----
__device__ __forceinline__ void arrive_flag(int* fl, int wid, int val) {
  asm volatile("s_waitcnt vmcnt(0)" ::: "memory");  // data stores complete first
  if ((threadIdx.x & 63) == 0)
    __hip_atomic_store(fl + wid, val, __ATOMIC_RELAXED, __HIP_MEMORY_SCOPE_AGENT);
}
__device__ __forceinline__ void wait_flags(const int* fl, int tgt) {
  const int* p = fl + (threadIdx.x & 31);
  for (;;) {
    int v = __hip_atomic_load(p, __ATOMIC_RELAXED, __HIP_MEMORY_SCOPE_AGENT);
    if (!__any(v < tgt)) break;
  }
}

// L1-bypassing 16B fragment load (two relaxed agent-scope u64 loads)
__device__ __forceinline__ short8 ld_frag(const short* p) {
  const u64* q = (const u64*)p;
  u64 lo = __hip_atomic_load(q, __ATOMIC_RELAXED, __HIP_MEMORY_SCOPE_AGENT);
  u64 hi = __hip_atomic_load(q + 1, __ATOMIC_RELAXED, __HIP_MEMORY_SCOPE_AGENT);
  short4v l4 = __builtin_bit_cast(short4v, lo);
  short4v h4 = __builtin_bit_cast(short4v, hi);
  return __builtin_shufflevector(l4, h4, 0, 1, 2, 3, 4, 5, 6, 7);
}

// ================== NEW: LDS-staged XCD-local GRU (mode 2) ==================
__global__ __launch_bounds__(256, 1) void gru_lds(
    const short* __restrict__ xp, const short* __restrict__ wfrag,
    short* __restrict__ hbuf, short* __restrict__ rhbuf,
    float* __restrict__ hfin, int* __restrict__ ctrl) {
  __shared__ short lds[4 * 8192];     // 4 x 16KB tiles: hA, hB, rhA, rhB
  __shared__ int s_slot, s_xcc;
  if (threadIdx.x == 0) {
    unsigned xcc;
    asm volatile("s_getreg_b32 %0, hwreg(HW_REG_XCC_ID)" : "=s"(xcc));
    xcc &= 7u;
    s_xcc = (int)xcc;
    s_slot = atomicAdd(ctrl + xcc * 16, 1);
  }
  __syncthreads();
  const int slot = s_slot;
  int* done = ctrl + 192;

  if (slot >= GROUP_WGS) {
    // ---- burner: low-power dependent-FMA spin keeps DPM clocks high ----
    float a = (float)threadIdx.x;
    for (;;) {
#pragma unroll
      for (int i = 0; i < 512; ++i) a = __builtin_fmaf(a, 1.0000001f, 1.0f);
      asm volatile("" : "+v"(a));
      if (__hip_atomic_load(done, __ATOMIC_RELAXED, __HIP_MEMORY_SCOPE_AGENT) >= 8)
        break;
    }
    asm volatile("" :: "v"(a));
    return;
  }

  const int group = s_xcc, member = slot;
  const int tid = threadIdx.x;
  const int w = tid >> 6, l = tid & 63, l15 = l & 15, lhi = l >> 4;
  const int cbg = member * 4 + w, jc = cbg * 16;
  const int rbA = group * 32, rbB = rbA + 16;

  // ---- weights (h-part) -> registers ----
  const short8* wf = (const short8*)wfrag;
  short8 wz[16], wr[16], wh[16];
#pragma unroll
  for (int kk = 0; kk < 16; ++kk) wz[kk] = wf[((cbg * 3 + 0) * 24 + kk) * 64 + l];
#pragma unroll
  for (int kk = 0; kk < 16; ++kk) wr[kk] = wf[((cbg * 3 + 1) * 24 + kk) * 64 + l];
#pragma unroll
  for (int kk = 0; kk < 16; ++kk) wh[kk] = wf[((cbg * 3 + 2) * 24 + kk) * 64 + l];

  const int drowA = rbA + lhi * 4, drowB = rbB + lhi * 4;
  const int dcol = jc + l15;

  const short* hbA_t = hbuf + (size_t)rbA * HH;     // 16KB tile bases
  const short* hbB_t = hbuf + (size_t)rbB * HH;
  const short* rhA_t = rhbuf + (size_t)rbA * HH;
  const short* rhB_t = rhbuf + (size_t)rbB * HH;

  const short* xpA[4];
  const short* xpB[4];
#pragma unroll
  for (int i = 0; i < 4; ++i) {
    xpA[i] = xp + (size_t)(drowA + i) * TT * HX + dcol;
    xpB[i] = xp + (size_t)(drowB + i) * TT * HX + dcol;
  }

  int* fb = ctrl + 256 + group * 128;
  int* rhAf = fb, *rhBf = fb + 32, *hAf = fb + 64, *hBf = fb + 96;

  float4v h_locA = {0.f, 0.f, 0.f, 0.f}, h_locB = {0.f, 0.f, 0.f, 0.f};
  short8 regsA[4], regsB[4], regsRA[4], regsRB[4];
  const short8 zero8 = {0, 0, 0, 0, 0, 0, 0, 0};
#pragma unroll
  for (int i = 0; i < 4; ++i) { regsA[i] = zero8; regsB[i] = zero8; }

  // t=0 x contributions (bias folded into xproj)
  float4v azxA, arxA, ahxA, azxB, arxB, ahxB;
#pragma unroll
  for (int i = 0; i < 4; ++i) {
    azxA[i] = bf2f(xpA[i][0]); arxA[i] = bf2f(xpA[i][512]); ahxA[i] = bf2f(xpA[i][1024]);
    azxB[i] = bf2f(xpB[i][0]); arxB[i] = bf2f(xpB[i][512]); ahxB[i] = bf2f(xpB[i][1024]);
  }
  unsigned short nzA[4], nrA[4], nhA[4], nzB[4], nrB[4], nhB[4];

  // LDS staging helpers (all-static indexing; XOR swizzle: idx ^= (row&7)<<3)
#define STAGE_WRITE(BUF, REGS)                                              \
  {                                                                         \
    _Pragma("unroll") for (int i_ = 0; i_ < 4; ++i_) {                      \
      int idx_ = w * 2048 + i_ * 512 + l * 8;                               \
      idx_ ^= ((w * 4 + i_) & 7) << 3;                                      \
      *(short8*)&lds[(BUF) * 8192 + idx_] = (REGS)[i_];                     \
    }                                                                       \
  }
#define STAGE_LOAD(REGS, GSRC)                                              \
  {                                                                         \
    _Pragma("unroll") for (int i_ = 0; i_ < 4; ++i_)                        \
      (REGS)[i_] = ld_frag((GSRC) + w * 2048 + i_ * 512 + l * 8);           \
  }
#define DSFRAG(BUF, KK)                                                     \
  (*(const short8*)&lds[(BUF) * 8192 +                                      \
      (((l15 << 9) | ((KK) * 32 + lhi * 8)) ^ ((l15 & 7) << 3))])

#pragma unroll 1
  for (int t = 0; t < TT; ++t) {
    // ===== P1A: z,r set A (tile already in regsA) =====
    STAGE_WRITE(0, regsA);
    __syncthreads();
    float4v zA, rrA;
    {
      float4v az = azxA, ar = arxA;
#pragma unroll
      for (int kk = 0; kk < 16; ++kk) {
        short8 a = DSFRAG(0, kk);
        az = mfma_bf16(a, wz[kk], az);
        ar = mfma_bf16(a, wr[kk], ar);
      }
#pragma unroll
      for (int i = 0; i < 4; ++i) { zA[i] = sigm(az[i]); rrA[i] = sigm(ar[i]); }
    }
#pragma unroll
    for (int i = 0; i < 4; ++i)
      rhbuf[(size_t)(drowA + i) * HH + dcol] = f2bf(rrA[i] * h_locA[i]);
    arrive_flag(rhAf, cbg, t + 1);
    if (t) { wait_flags(hBf, t); STAGE_LOAD(regsB, hbB_t); }  // prefetch for P1B

    // ===== P1B =====
    STAGE_WRITE(1, regsB);
    __syncthreads();
    float4v zB, rrB;
    {
      float4v az = azxB, ar = arxB;
#pragma unroll
      for (int kk = 0; kk < 16; ++kk) {
        short8 a = DSFRAG(1, kk);
        az = mfma_bf16(a, wz[kk], az);
        ar = mfma_bf16(a, wr[kk], ar);
      }
#pragma unroll
      for (int i = 0; i < 4; ++i) { zB[i] = sigm(az[i]); rrB[i] = sigm(ar[i]); }
    }
#pragma unroll
    for (int i = 0; i < 4; ++i)
      rhbuf[(size_t)(drowB + i) * HH + dcol] = f2bf(rrB[i] * h_locB[i]);
    arrive_flag(rhBf, cbg, t + 1);
    wait_flags(rhAf, t + 1); STAGE_LOAD(regsRA, rhA_t);       // prefetch for P2A

    // ===== P2A: h_tilde + update set A =====
    STAGE_WRITE(2, regsRA);
    __syncthreads();
    {
      float4v ah = ahxA;
#pragma unroll
      for (int kk = 0; kk < 16; ++kk)
        ah = mfma_bf16(DSFRAG(2, kk), wh[kk], ah);
#pragma unroll
      for (int i = 0; i < 4; ++i) {
        float hv = tanh_(ah[i]);
        h_locA[i] = (1.0f - zA[i]) * h_locA[i] + zA[i] * hv;
      }
    }
    if (t + 1 < TT) {
#pragma unroll
      for (int i = 0; i < 4; ++i)
        hbuf[(size_t)(drowA + i) * HH + dcol] = f2bf(h_locA[i]);
      arrive_flag(hAf, cbg, t + 1);
    } else {
#pragma unroll
      for (int i = 0; i < 4; ++i)
        hfin[(size_t)(drowA + i) * HH + dcol] = h_locA[i];
    }
    wait_flags(rhBf, t + 1); STAGE_LOAD(regsRB, rhB_t);       // prefetch for P2B
    // x prefetch for t+1 (plain cached loads; plenty of slack)
    if (t + 1 < TT) {
      size_t toff = (size_t)(t + 1) * HX;
#pragma unroll
      for (int i = 0; i < 4; ++i) {
        nzA[i] = *(const unsigned short*)(xpA[i] + toff);
        nrA[i] = *(const unsigned short*)(xpA[i] + toff + 512);
        nhA[i] = *(const unsigned short*)(xpA[i] + toff + 1024);
        nzB[i] = *(const unsigned short*)(xpB[i] + toff);
        nrB[i] = *(const unsigned short*)(xpB[i] + toff + 512);
        nhB[i] = *(const unsigned short*)(xpB[i] + toff + 1024);
      }
    }

    // ===== P2B =====
    STAGE_WRITE(3, regsRB);
    __syncthreads();
    {
      float4v ah = ahxB;
#pragma unroll
      for (int kk = 0; kk < 16; ++kk)
        ah = mfma_bf16(DSFRAG(3, kk), wh[kk], ah);
#pragma unroll
      for (int i = 0; i < 4; ++i) {
        float hv = tanh_(ah[i]);
        h_locB[i] = (1.0f - zB[i]) * h_locB[i] + zB[i] * hv;
      }
    }
    if (t + 1 < TT) {
#pragma unroll
      for (int i = 0; i < 4; ++i)
        hbuf[(size_t)(drowB + i) * HH + dcol] = f2bf(h_locB[i]);
      arrive_flag(hBf, cbg, t + 1);
      wait_flags(hAf, t + 1); STAGE_LOAD(regsA, hbA_t);       // prefetch next P1A
      // next-step x contributions
#pragma unroll
      for (int i = 0; i < 4; ++i) {
        azxA[i] = bf2f(nzA[i]); arxA[i] = bf2f(nrA[i]); ahxA[i] = bf2f(nhA[i]);
        azxB[i] = bf2f(nzB[i]); arxB[i] = bf2f(nrB[i]); ahxB[i] = bf2f(nhB[i]);
      }
    } else {
#pragma unroll
      for (int i = 0; i < 4; ++i)
        hfin[(size_t)(drowB + i) * HH + dcol] = h_locB[i];
    }
  }

  if (member == 0 && tid == 0)
    __hip_atomic_fetch_add(done, 1, __ATOMIC_RELAXED, __HIP_MEMORY_SCOPE_AGENT);
#undef STAGE_WRITE
#undef STAGE_LOAD
#undef DSFRAG
}

// ================== fallback (modes 1/0): R8 kernel, unchanged ==================
__device__ __forceinline__ void gate_phase1(const short* hb_lane,
    const short8* wz, const short8* wr, float4v azx, float4v arx,
    float bz, float br, float4v& z, float4v& rr) {
  short8 a[16];
#pragma unroll
  for (int kk = 0; kk < 16; ++kk) a[kk] = ld_frag(hb_lane + kk * 32);
  float4v az = azx, ar = arx;
#pragma unroll
  for (int kk = 0; kk < 16; ++kk) {
    az = mfma_bf16(a[kk], wz[kk], az);
    ar = mfma_bf16(a[kk], wr[kk], ar);
  }
#pragma unroll
  for (int i = 0; i < 4; ++i) {
    z[i] = sigm(az[i] + bz);
    rr[i] = sigm(ar[i] + br);
  }
}
__device__ __forceinline__ float4v gate_phase2(const short* rh_lane,
    const short8* wh, float4v ahx, float bh, float4v z, float4v h_loc) {
  short8 a[16];
#pragma unroll
  for (int kk = 0; kk < 16; ++kk) a[kk] = ld_frag(rh_lane + kk * 32);
  float4v ah = ahx;
#pragma unroll
  for (int kk = 0; kk < 16; ++kk)
    ah = mfma_bf16(a[kk], wh[kk], ah);
  float4v hn;
#pragma unroll
  for (int i = 0; i < 4; ++i) {
    float hv = tanh_(ah[i] + bh);
    hn[i] = (1.0f - z[i]) * h_loc[i] + z[i] * hv;
  }
  return hn;
}
template <bool XB>
__device__ __forceinline__ void load_xf(short8 (&xf)[8], const short* xb_l,
                                        const float* xf_l, int t) {
#pragma unroll
  for (int kx = 0; kx < 8; ++kx) {
    if constexpr (XB) {
      xf[kx] = *(const short8*)(xb_l + (size_t)t * FF + kx * 32);
    } else {
      const float* xl = xf_l + (size_t)t * FF;
      float4v a = *(const float4v*)(xl + kx * 32);
      float4v b2 = *(const float4v*)(xl + kx * 32 + 4);
      short8 v;
      v[0] = f2bf(a[0]); v[1] = f2bf(a[1]); v[2] = f2bf(a[2]); v[3] = f2bf(a[3]);
      v[4] = f2bf(b2[0]); v[5] = f2bf(b2[1]); v[6] = f2bf(b2[2]); v[7] = f2bf(b2[3]);
      xf[kx] = v;
    }
  }
}
__device__ __forceinline__ void prime_x(const short8 (&xf)[8],
    const short8* wz, const short8* wr, const short8* wh,
    float4v& azx, float4v& arx, float4v& ahx) {
  azx = (float4v){0.f, 0.f, 0.f, 0.f};
  arx = (float4v){0.f, 0.f, 0.f, 0.f};
  ahx = (float4v){0.f, 0.f, 0.f, 0.f};
#pragma unroll
  for (int kx = 0; kx < 8; ++kx) {
    azx = mfma_bf16(xf[kx], wz[16 + kx], azx);
    arx = mfma_bf16(xf[kx], wr[16 + kx], arx);
    ahx = mfma_bf16(xf[kx], wh[16 + kx], ahx);
  }
}
template <int XM>
__global__ __launch_bounds__(256, 1) void gru_kernel(
    const void* __restrict__ xv, const short* __restrict__ wfrag,
    short* __restrict__ hbuf, short* __restrict__ rhbuf,
    float* __restrict__ hfin, int* __restrict__ ctrl,
    const float* __restrict__ bzv, const float* __restrict__ brv,
    const float* __restrict__ bhv) {
  __shared__ int s_slot, s_xcc;
  if (threadIdx.x == 0) {
    unsigned xcc;
    asm volatile("s_getreg_b32 %0, hwreg(HW_REG_XCC_ID)" : "=s"(xcc));
    xcc &= 7u;
    s_xcc = (int)xcc;
    s_slot = atomicAdd(ctrl + xcc * 16, 1);
  }
  __syncthreads();
  const int slot = s_slot;
  if (slot >= GROUP_WGS) return;
  const int group = s_xcc;
  const int member = slot;
  const int tid = threadIdx.x;
  const int w = tid >> 6;
  const int l = tid & 63;
  const int l15 = l & 15;
  const int lhi = l >> 4;
  const int cbg = member * 4 + w;
  const int jc = cbg * 16;
  const int rbA = group * 32;
  const int rbB = rbA + 16;
  const short8* wf = (const short8*)wfrag;
  short8 wz[24], wr[24], wh[24];
#pragma unroll
  for (int kk = 0; kk < 24; ++kk) wz[kk] = wf[((cbg * 3 + 0) * 24 + kk) * 64 + l];
#pragma unroll
  for (int kk = 0; kk < 24; ++kk) wr[kk] = wf[((cbg * 3 + 1) * 24 + kk) * 64 + l];
#pragma unroll
  for (int kk = 0; kk < 24; ++kk) wh[kk] = wf[((cbg * 3 + 2) * 24 + kk) * 64 + l];
  const float bz = bzv[jc + l15], br = brv[jc + l15], bh = bhv[jc + l15];
  const int drowA = rbA + lhi * 4, drowB = rbB + lhi * 4;
  const int dcol = jc + l15;
  const short* hbA = hbuf + (size_t)(rbA + l15) * HH + lhi * 8;
  const short* hbB = hbuf + (size_t)(rbB + l15) * HH + lhi * 8;
  const short* rhA = rhbuf + (size_t)(rbA + l15) * HH + lhi * 8;
  const short* rhB = rhbuf + (size_t)(rbB + l15) * HH + lhi * 8;
  const float* xfA32 = (XM == 0) ? ((const float*)xv + (size_t)(rbA + l15) * TT * FF + lhi * 8) : nullptr;
  const float* xfB32 = (XM == 0) ? ((const float*)xv + (size_t)(rbB + l15) * TT * FF + lhi * 8) : nullptr;
  const short* xbA = (XM == 1) ? ((const short*)xv + (size_t)(rbA + l15) * TT * FF + lhi * 8) : nullptr;
  const short* xbB = (XM == 1) ? ((const short*)xv + (size_t)(rbB + l15) * TT * FF + lhi * 8) : nullptr;
  float4v h_locA = {0.f, 0.f, 0.f, 0.f}, h_locB = {0.f, 0.f, 0.f, 0.f};
  int* fb = ctrl + 256 + group * 128;
  int* rhAf = fb, * rhBf = fb + 32, * hAf = fb + 64, * hBf = fb + 96;
  float4v azxA, arxA, ahxA, azxB, arxB, ahxB;
  {
    short8 xf[8];
    load_xf<XM == 1>(xf, xbA, xfA32, 0);
    prime_x(xf, wz, wr, wh, azxA, arxA, ahxA);
    load_xf<XM == 1>(xf, xbB, xfB32, 0);
    prime_x(xf, wz, wr, wh, azxB, arxB, ahxB);
  }
#pragma unroll 1
  for (int t = 0; t < TT; ++t) {
    if (t) wait_flags(hAf, t);
    float4v zA, rrA;
    gate_phase1(hbA, wz, wr, azxA, arxA, bz, br, zA, rrA);
#pragma unroll
    for (int i = 0; i < 4; ++i)
      rhbuf[(size_t)(drowA + i) * HH + dcol] = f2bf(rrA[i] * h_locA[i]);
    arrive_flag(rhAf, cbg, t + 1);
    if (t) wait_flags(hBf, t);
    float4v zB, rrB;
    gate_phase1(hbB, wz, wr, azxB, arxB, bz, br, zB, rrB);
#pragma unroll
    for (int i = 0; i < 4; ++i)
      rhbuf[(size_t)(drowB + i) * HH + dcol] = f2bf(rrB[i] * h_locB[i]);
    arrive_flag(rhBf, cbg, t + 1);
    wait_flags(rhAf, t + 1);
    h_locA = gate_phase2(rhA, wh, ahxA, bh, zA, h_locA);
    if (t + 1 < TT) {
#pragma unroll
      for (int i = 0; i < 4; ++i)
        hbuf[(size_t)(drowA + i) * HH + dcol] = f2bf(h_locA[i]);
      arrive_flag(hAf, cbg, t + 1);
    } else {
#pragma unroll
      for (int i = 0; i < 4; ++i)
        hfin[(size_t)(drowA + i) * HH + dcol] = h_locA[i];
    }
    wait_flags(rhBf, t + 1);
    h_locB = gate_phase2(rhB, wh, ahxB, bh, zB, h_locB);
    if (t + 1 < TT) {
#pragma unroll
      for (int i = 0; i < 4; ++i)
        hbuf[(size_t)(drowB + i) * HH + dcol] = f2bf(h_locB[i]);
      arrive_flag(hBf, cbg, t + 1);
    } else {
#pragma unroll
      for (int i = 0; i < 4; ++i)
        hfin[(size_t)(drowB + i) * HH + dcol] = h_locB[i];
    }
    if (t + 1 < TT) {
      short8 xf[8];
      load_xf<XM == 1>(xf, xbA, xfA32, t + 1);
      prime_x(xf, wz, wr, wh, azxA, arxA, ahxA);
      load_xf<XM == 1>(xf, xbB, xfB32, t + 1);
      prime_x(xf, wz, wr, wh, azxB, arxB, ahxB);
    }
  }
}

// out[b, c] = h_final[b,:] @ fc_w[:,c] + fc_b[c]
__global__ void fc_kernel(const float* __restrict__ hfin, const float* __restrict__ fw,
                          const float* __restrict__ fb, float* __restrict__ out) {
  int b = blockIdx.x;
  int tid = threadIdx.x;  // 64
  float p[10];
#pragma unroll
  for (int c = 0; c < 10; ++c) p[c] = 0.f;
  for (int k = tid; k < HH; k += 64) {
    float hv = hfin[(size_t)b * HH + k];
#pragma unroll
    for (int c = 0; c < 10; ++c) p[c] += hv * fw[k * 10 + c];
  }
#pragma unroll
  for (int c = 0; c < 10; ++c) {
    float v = p[c];
    for (int off = 32; off > 0; off >>= 1) v += __shfl_down(v, off);
    if (tid == 0) out[b * 10 + c] = v + fb[c];
  }
}

extern "C" void kernel_launch(void* const* d_in, const int* in_sizes, int n_in,
                              void* d_out, int out_size, void* d_ws, size_t ws_size,
                              hipStream_t stream) {
  const float* x = (const float*)d_in[0];
  const float* Wz_w = (const float*)d_in[1];
  const float* Wz_b = (const float*)d_in[2];
  const float* Wr_w = (const float*)d_in[3];
  const float* Wr_b = (const float*)d_in[4];
  const float* Wh_w = (const float*)d_in[5];
  const float* Wh_b = (const float*)d_in[6];
  const float* fc_w = (const float*)d_in[7];
  const float* fc_b = (const float*)d_in[8];

  char* ws = (char*)d_ws;
  short* wfrag = (short*)(ws + WFRAG_OFF);
  short* hbuf = (short*)(ws + HBUF_OFF);
  short* rhbuf = (short*)(ws + RHBUF_OFF);
  float* hfin = (float*)(ws + HFIN_OFF);
  int* ctrl = (int*)(ws + CTRL_OFF);
  short* xbase = (short*)(ws + XBASE_OFF);

  // h0 = 0, claim + done + flag arrays = 0 (EVERY launch)
  hipMemsetAsync(hbuf, 0, BB * HH * 2, stream);
  hipMemsetAsync(ctrl, 0, CTRL_BYTES, stream);

  prep_w<<<576, 256, 0, stream>>>(Wz_w, Wr_w, Wh_w, wfrag);

  if (ws_size >= WS_M2) {
    xproj_gemm<<<BB * TT / 64, 256, 0, stream>>>(x, wfrag, Wz_b, Wr_b, Wh_b, xbase);
    gru_lds<<<256, 256, 0, stream>>>(xbase, wfrag, hbuf, rhbuf, hfin, ctrl);
  } else if (ws_size >= WS_M1) {
    xprep<<<(BB * TT * FF / 8) / 256, 256, 0, stream>>>(x, xbase);
    gru_kernel<1><<<256, 256, 0, stream>>>(xbase, wfrag, hbuf, rhbuf, hfin, ctrl,
                                           Wz_b, Wr_b, Wh_b);
  } else {
    gru_kernel<0><<<256, 256, 0, stream>>>(x, wfrag, hbuf, rhbuf, hfin, ctrl,
                                           Wz_b, Wr_b, Wh_b);
  }
  fc_kernel<<<BB, 64, 0, stream>>>(hfin, fc_w, fc_b, (float*)d_out);
}